// Round 2
// baseline (1594.034 us; speedup 1.0000x reference)
//
#include <hip/hip_runtime.h>
#include <hip/hip_bf16.h>
#include <math.h>

typedef __hip_bfloat16 bf16;
typedef __attribute__((ext_vector_type(8))) short short8;
typedef __attribute__((ext_vector_type(4))) float floatx4;

constexpr int Bc = 4, Sc = 1024, Dc = 2048, Hc = 16, HDc = 128, Ic = 8192;

__device__ __forceinline__ float bf2f(bf16 x){ return __bfloat162float(x); }
__device__ __forceinline__ bf16 f2bf(float x){ return __float2bfloat16(x); }

__device__ __forceinline__ uint4 pack8(float4 a, float4 b){
    union { uint4 u; bf16 h[8]; } r;
    r.h[0]=f2bf(a.x); r.h[1]=f2bf(a.y); r.h[2]=f2bf(a.z); r.h[3]=f2bf(a.w);
    r.h[4]=f2bf(b.x); r.h[5]=f2bf(b.y); r.h[6]=f2bf(b.z); r.h[7]=f2bf(b.w);
    return r.u;
}

// ---- dtype probe: ln1_w is all-ones. fp32 one = 0x3F800000; bf16 pair = 0x3F803F80.
__global__ void detect_kernel(const void* __restrict__ probe, int* __restrict__ flag){
    if (threadIdx.x == 0)
        *flag = (((const unsigned*)probe)[0] == 0x3F800000u) ? 1 : 0;
}

// ---- hidden_states -> bf16 copy in ws (8M elements, 8 per thread)
__global__ __launch_bounds__(256)
void conv_kernel(const void* __restrict__ src, bf16* __restrict__ dst, const int* __restrict__ flagp){
    const bool f32 = (*flagp != 0);
    const size_t i = ((size_t)blockIdx.x * 256 + threadIdx.x) * 8;
    if (f32) {
        const float* s = (const float*)src;
        float4 a = *(const float4*)(s + i);
        float4 b = *(const float4*)(s + i + 4);
        *(uint4*)(dst + i) = pack8(a, b);
    } else {
        *(uint4*)(dst + i) = *(const uint4*)((const bf16*)src + i);
    }
}

// ---- LayerNorm: one block per row, D=2048, 256 thr x 8 el; x is bf16 (ws), w/b dtype-flagged
__global__ __launch_bounds__(256)
void ln_kernel(const bf16* __restrict__ x, const void* __restrict__ w,
               const void* __restrict__ b, bf16* __restrict__ y, const int* __restrict__ flagp)
{
    const bool f32 = (*flagp != 0);
    const int row = blockIdx.x;
    const int t = threadIdx.x;
    union { uint4 u; bf16 h[8]; } ld;
    ld.u = *(const uint4*)&x[(size_t)row * Dc + t * 8];
    float f[8], s = 0.f, s2 = 0.f;
#pragma unroll
    for (int j = 0; j < 8; ++j) { f[j] = bf2f(ld.h[j]); s += f[j]; s2 += f[j] * f[j]; }
#pragma unroll
    for (int off = 32; off; off >>= 1) { s += __shfl_xor(s, off); s2 += __shfl_xor(s2, off); }
    __shared__ float red[8];
    const int wave = t >> 6, lane = t & 63;
    if (lane == 0) { red[wave] = s; red[4 + wave] = s2; }
    __syncthreads();
    s  = red[0] + red[1] + red[2] + red[3];
    s2 = red[4] + red[5] + red[6] + red[7];
    const float mean = s * (1.0f / Dc);
    const float var  = s2 * (1.0f / Dc) - mean * mean;
    const float rs   = rsqrtf(var + 1e-5f);
    union { uint4 u; bf16 h[8]; } st;
#pragma unroll
    for (int j = 0; j < 8; ++j) {
        const int col = t * 8 + j;
        const float wv = f32 ? ((const float*)w)[col] : bf2f(((const bf16*)w)[col]);
        const float bv = f32 ? ((const float*)b)[col] : bf2f(((const bf16*)b)[col]);
        st.h[j] = f2bf((f[j] - mean) * rs * wv + bv);
    }
    *(uint4*)&y[(size_t)row * Dc + t * 8] = st.u;
}

// ---- GEMM C[M,N] = epi(A[M,K] @ W[N,K]^T + bias); A/res bf16 (ws), W/bias dtype-flagged.
// EPI: 0 plain, 1 *scale, 2 exact GELU, 3 +residual
template<int EPI>
__global__ __launch_bounds__(256)
void gemm_bt(const bf16* __restrict__ A, const void* __restrict__ W,
             const void* __restrict__ bias, const bf16* __restrict__ res,
             void* __restrict__ C, int M, int N, int K, float scale,
             const int* __restrict__ flagp, int out_f32_en)
{
    const bool f32 = (*flagp != 0);
    __shared__ __align__(16) bf16 As[128 * 32];
    __shared__ __align__(16) bf16 Bs[128 * 32];
    const int tile_m = blockIdx.y * 128;
    const int tile_n = blockIdx.x * 128;
    const int t = threadIdx.x;
    const int wave = t >> 6, lane = t & 63, quad = lane >> 4, l16 = lane & 15;
    const int wm = (wave >> 1) * 64, wn = (wave & 1) * 64;
    const int srow = t >> 2, scol = (t & 3) * 8;

    floatx4 acc[4][4] = {};

    const bf16* Aptr  = A + (size_t)(tile_m + srow) * K + scol;
    const bf16* A2ptr = A + (size_t)(tile_m + 64 + srow) * K + scol;
    const size_t woff  = (size_t)(tile_n + srow) * K + scol;
    const size_t woff2 = (size_t)(tile_n + 64 + srow) * K + scol;

    for (int k0 = 0; k0 < K; k0 += 32) {
        __syncthreads();
        *(uint4*)&As[srow * 32 + scol]        = *(const uint4*)(Aptr  + k0);
        *(uint4*)&As[(64 + srow) * 32 + scol] = *(const uint4*)(A2ptr + k0);
        if (f32) {
            const float* Wf = (const float*)W;
            *(uint4*)&Bs[srow * 32 + scol] =
                pack8(*(const float4*)(Wf + woff + k0), *(const float4*)(Wf + woff + k0 + 4));
            *(uint4*)&Bs[(64 + srow) * 32 + scol] =
                pack8(*(const float4*)(Wf + woff2 + k0), *(const float4*)(Wf + woff2 + k0 + 4));
        } else {
            const bf16* Wb = (const bf16*)W;
            *(uint4*)&Bs[srow * 32 + scol]        = *(const uint4*)(Wb + woff + k0);
            *(uint4*)&Bs[(64 + srow) * 32 + scol] = *(const uint4*)(Wb + woff2 + k0);
        }
        __syncthreads();
        short8 af[4], bfr[4];
#pragma unroll
        for (int mi = 0; mi < 4; ++mi)
            af[mi] = *(const short8*)&As[(wm + mi * 16 + l16) * 32 + quad * 8];
#pragma unroll
        for (int ni = 0; ni < 4; ++ni)
            bfr[ni] = *(const short8*)&Bs[(wn + ni * 16 + l16) * 32 + quad * 8];
#pragma unroll
        for (int mi = 0; mi < 4; ++mi)
#pragma unroll
            for (int ni = 0; ni < 4; ++ni)
                acc[mi][ni] = __builtin_amdgcn_mfma_f32_16x16x32_bf16(af[mi], bfr[ni], acc[mi][ni], 0, 0, 0);
    }

    const bool of32 = f32 && (out_f32_en != 0);
#pragma unroll
    for (int mi = 0; mi < 4; ++mi) {
        const int row0 = tile_m + wm + mi * 16 + quad * 4;
#pragma unroll
        for (int ni = 0; ni < 4; ++ni) {
            const int col = tile_n + wn + ni * 16 + l16;
            const float bv = f32 ? ((const float*)bias)[col] : bf2f(((const bf16*)bias)[col]);
#pragma unroll
            for (int r = 0; r < 4; ++r) {
                float v = acc[mi][ni][r] + bv;
                if (EPI == 1) v *= scale;
                if (EPI == 2) v = 0.5f * v * (1.0f + erff(v * 0.70710678118f));
                const size_t idx = (size_t)(row0 + r) * N + col;
                if (EPI == 3) v += bf2f(res[idx]);
                if (of32) ((float*)C)[idx] = v;
                else      ((bf16*)C)[idx] = f2bf(v);
            }
        }
    }
}

// ---- Flash attention: one block per (64 q-rows, b*h); Q/K/V bf16 (ws), mask dtype-flagged
__global__ __launch_bounds__(256)
void flash_attn(const bf16* __restrict__ Q, const bf16* __restrict__ K,
                const bf16* __restrict__ V, const void* __restrict__ mask,
                bf16* __restrict__ O, const int* __restrict__ flagp)
{
    const bool f32 = (*flagp != 0);
    __shared__ __align__(16) bf16 Ks[32 * 128];
    __shared__ __align__(16) bf16 Vt[128 * 32];
    __shared__ __align__(16) bf16 Ps[4][16 * 32];
    const int bh = blockIdx.y, b = bh / Hc, h = bh % Hc;
    const int t = threadIdx.x, wave = t >> 6, lane = t & 63, quad = lane >> 4, l16 = lane & 15;
    const int qbase = blockIdx.x * 64 + wave * 16;
    const size_t base = (size_t)b * Sc * Dc + (size_t)h * HDc;

    short8 qf[4];
    {
        const bf16* qp = Q + base + (size_t)(qbase + l16) * Dc + quad * 8;
#pragma unroll
        for (int kc = 0; kc < 4; ++kc) qf[kc] = *(const short8*)(qp + kc * 32);
    }
    float m_i[4], l_i[4];
    floatx4 Oacc[8] = {};
#pragma unroll
    for (int r = 0; r < 4; ++r) { m_i[r] = -1e30f; l_i[r] = 0.f; }

    const int srow = t >> 4, scol = (t & 15) * 8;

    for (int kt = 0; kt < Sc; kt += 32) {
        __syncthreads();
#pragma unroll
        for (int c = 0; c < 2; ++c) {
            const int row = c * 16 + srow;
            const size_t g = base + (size_t)(kt + row) * Dc + scol;
            *(uint4*)&Ks[row * 128 + scol] = *(const uint4*)&K[g];
            union { uint4 u; bf16 e[8]; } vv;
            vv.u = *(const uint4*)&V[g];
#pragma unroll
            for (int j = 0; j < 8; ++j) Vt[(scol + j) * 32 + row] = vv.e[j];
        }
        __syncthreads();

        floatx4 sacc[2] = {};
#pragma unroll
        for (int sub = 0; sub < 2; ++sub)
#pragma unroll
            for (int kc = 0; kc < 4; ++kc) {
                short8 kf = *(const short8*)&Ks[(sub * 16 + l16) * 128 + kc * 32 + quad * 8];
                sacc[sub] = __builtin_amdgcn_mfma_f32_16x16x32_bf16(qf[kc], kf, sacc[sub], 0, 0, 0);
            }
#pragma unroll
        for (int sub = 0; sub < 2; ++sub) {
            const int ki = b * Sc + kt + sub * 16 + l16;
            const float mv = f32 ? ((const float*)mask)[ki] : bf2f(((const bf16*)mask)[ki]);
            const float madd = (mv < 0.5f) ? -1e30f : 0.f;
#pragma unroll
            for (int r = 0; r < 4; ++r) sacc[sub][r] += madd;
        }
        float p0[4], p1[4], alpha[4];
#pragma unroll
        for (int r = 0; r < 4; ++r) {
            float mx = fmaxf(sacc[0][r], sacc[1][r]);
#pragma unroll
            for (int off = 8; off; off >>= 1) mx = fmaxf(mx, __shfl_xor(mx, off));
            const float mnew = fmaxf(m_i[r], mx);
            alpha[r] = expf(m_i[r] - mnew);
            p0[r] = expf(sacc[0][r] - mnew);
            p1[r] = expf(sacc[1][r] - mnew);
            float ps = p0[r] + p1[r];
#pragma unroll
            for (int off = 8; off; off >>= 1) ps += __shfl_xor(ps, off);
            l_i[r] = l_i[r] * alpha[r] + ps;
            m_i[r] = mnew;
        }
#pragma unroll
        for (int nsub = 0; nsub < 8; ++nsub)
#pragma unroll
            for (int r = 0; r < 4; ++r) Oacc[nsub][r] *= alpha[r];

        bf16* Pw = Ps[wave];
#pragma unroll
        for (int r = 0; r < 4; ++r) {
            Pw[(quad * 4 + r) * 32 + l16]      = f2bf(p0[r]);
            Pw[(quad * 4 + r) * 32 + 16 + l16] = f2bf(p1[r]);
        }
        __syncthreads();
        const short8 pf = *(const short8*)&Pw[l16 * 32 + quad * 8];
#pragma unroll
        for (int nsub = 0; nsub < 8; ++nsub) {
            short8 vf = *(const short8*)&Vt[(nsub * 16 + l16) * 32 + quad * 8];
            Oacc[nsub] = __builtin_amdgcn_mfma_f32_16x16x32_bf16(pf, vf, Oacc[nsub], 0, 0, 0);
        }
    }

#pragma unroll
    for (int r = 0; r < 4; ++r) {
        const float inv = 1.f / l_i[r];
        const size_t rowbase = base + (size_t)(qbase + quad * 4 + r) * Dc;
#pragma unroll
        for (int nsub = 0; nsub < 8; ++nsub)
            O[rowbase + nsub * 16 + l16] = f2bf(Oacc[nsub][r] * inv);
    }
}

// ---------------------------------- launcher ------------------------------------------
extern "C" void kernel_launch(void* const* d_in, const int* in_sizes, int n_in,
                              void* d_out, int out_size, void* d_ws, size_t ws_size,
                              hipStream_t stream)
{
    const void* hidden = d_in[1];
    const void* amask  = d_in[2];
    const void* Wq = d_in[4];  const void* bq = d_in[5];
    const void* Wk = d_in[6];  const void* bk = d_in[7];
    const void* Wv = d_in[8];  const void* bv = d_in[9];
    const void* Wo = d_in[10]; const void* bo = d_in[11];
    const void* ln1w = d_in[12]; const void* ln1b = d_in[13];
    const void* ln2w = d_in[14]; const void* ln2b = d_in[15];
    const void* W1 = d_in[16]; const void* b1 = d_in[17];
    const void* W2 = d_in[18]; const void* b2 = d_in[19];

    const size_t MD = (size_t)Bc * Sc * Dc;   // 8M elements
    int*  flagp = (int*)d_ws;
    bf16* base  = (bf16*)((char*)d_ws + 16);
    bf16* x_ln   = base;             // region 0..32M also reused by ffn1 later
    bf16* q      = base + MD;
    bf16* k      = base + 2 * MD;
    bf16* v      = base + 3 * MD;
    bf16* attn   = base + 4 * MD;
    bf16* hid_bf = base + 5 * MD;
    bf16* hid2   = base + 6 * MD;
    bf16* y_ln   = base + 7 * MD;
    bf16* ffn1   = base;             // 32M el, overlays x_ln/q/k/v (all dead by then)

    const float scale = 0.08838834764831845f; // 128^-0.5

    detect_kernel<<<1, 64, 0, stream>>>(ln1w, flagp);
    conv_kernel<<<MD / (256 * 8), 256, 0, stream>>>(hidden, hid_bf, flagp);
    ln_kernel<<<Bc * Sc, 256, 0, stream>>>(hid_bf, ln1w, ln1b, x_ln, flagp);
    gemm_bt<1><<<dim3(Dc / 128, Bc * Sc / 128), 256, 0, stream>>>(x_ln, Wq, bq, nullptr, q, Bc * Sc, Dc, Dc, scale, flagp, 0);
    gemm_bt<0><<<dim3(Dc / 128, Bc * Sc / 128), 256, 0, stream>>>(x_ln, Wk, bk, nullptr, k, Bc * Sc, Dc, Dc, 0.f, flagp, 0);
    gemm_bt<0><<<dim3(Dc / 128, Bc * Sc / 128), 256, 0, stream>>>(x_ln, Wv, bv, nullptr, v, Bc * Sc, Dc, Dc, 0.f, flagp, 0);
    flash_attn<<<dim3(Sc / 64, Bc * Hc), 256, 0, stream>>>(q, k, v, amask, attn, flagp);
    gemm_bt<3><<<dim3(Dc / 128, Bc * Sc / 128), 256, 0, stream>>>(attn, Wo, bo, hid_bf, hid2, Bc * Sc, Dc, Dc, 0.f, flagp, 0);
    ln_kernel<<<Bc * Sc, 256, 0, stream>>>(hid2, ln2w, ln2b, y_ln, flagp);
    gemm_bt<2><<<dim3(Ic / 128, Bc * Sc / 128), 256, 0, stream>>>(y_ln, W1, b1, nullptr, ffn1, Bc * Sc, Ic, Dc, 0.f, flagp, 0);
    gemm_bt<3><<<dim3(Dc / 128, Bc * Sc / 128), 256, 0, stream>>>(ffn1, W2, b2, hid2, d_out, Bc * Sc, Dc, Ic, 0.f, flagp, 1);
}

// Round 3
// 1150.260 us; speedup vs baseline: 1.3858x; 1.3858x over previous
//
#include <hip/hip_runtime.h>
#include <hip/hip_bf16.h>
#include <math.h>

typedef __hip_bfloat16 bf16;
typedef __attribute__((ext_vector_type(8))) short short8;
typedef __attribute__((ext_vector_type(4))) float floatx4;

constexpr int Bc = 4, Sc = 1024, Dc = 2048, Hc = 16, HDc = 128, Ic = 8192;

__device__ __forceinline__ float bf2f(bf16 x){ return __bfloat162float(x); }
__device__ __forceinline__ bf16 f2bf(float x){ return __float2bfloat16(x); }

__device__ __forceinline__ uint4 pack8(float4 a, float4 b){
    union { uint4 u; bf16 h[8]; } r;
    r.h[0]=f2bf(a.x); r.h[1]=f2bf(a.y); r.h[2]=f2bf(a.z); r.h[3]=f2bf(a.w);
    r.h[4]=f2bf(b.x); r.h[5]=f2bf(b.y); r.h[6]=f2bf(b.z); r.h[7]=f2bf(b.w);
    return r.u;
}

// async global->LDS, 16B/lane; lds must be the WAVE-UNIFORM base (deposit = base + lane*16)
__device__ __forceinline__ void glds16(void* lds, const void* g){
    __builtin_amdgcn_global_load_lds(
        (__attribute__((address_space(1))) void*)(size_t)g,
        (__attribute__((address_space(3))) void*)lds,
        16, 0, 0);
}

// ---- weight convert fp32 -> bf16, 8 el/thread -----------------------------------------
__global__ __launch_bounds__(256)
void conv_w(const float* __restrict__ src, bf16* __restrict__ dst){
    const size_t i = ((size_t)blockIdx.x * 256 + threadIdx.x) * 8;
    float4 a = *(const float4*)(src + i);
    float4 b = *(const float4*)(src + i + 4);
    *(uint4*)(dst + i) = pack8(a, b);
}

// ---- LayerNorm: one block per row, D=2048, 256 thr x 8 el; INF32: input dtype ---------
template<int INF32>
__global__ __launch_bounds__(256)
void ln_kernel(const void* __restrict__ x, const float* __restrict__ w,
               const float* __restrict__ b, bf16* __restrict__ y)
{
    const int row = blockIdx.x;
    const int t = threadIdx.x;
    float f[8], s = 0.f, s2 = 0.f;
    if (INF32) {
        const float* xr = (const float*)x + (size_t)row * Dc + t * 8;
        float4 a = *(const float4*)xr, c = *(const float4*)(xr + 4);
        f[0]=a.x; f[1]=a.y; f[2]=a.z; f[3]=a.w; f[4]=c.x; f[5]=c.y; f[6]=c.z; f[7]=c.w;
    } else {
        union { uint4 u; bf16 h[8]; } ld;
        ld.u = *(const uint4*)((const bf16*)x + (size_t)row * Dc + t * 8);
#pragma unroll
        for (int j = 0; j < 8; ++j) f[j] = bf2f(ld.h[j]);
    }
#pragma unroll
    for (int j = 0; j < 8; ++j) { s += f[j]; s2 += f[j] * f[j]; }
#pragma unroll
    for (int off = 32; off; off >>= 1) { s += __shfl_xor(s, off); s2 += __shfl_xor(s2, off); }
    __shared__ float red[8];
    const int wave = t >> 6, lane = t & 63;
    if (lane == 0) { red[wave] = s; red[4 + wave] = s2; }
    __syncthreads();
    s  = red[0] + red[1] + red[2] + red[3];
    s2 = red[4] + red[5] + red[6] + red[7];
    const float mean = s * (1.0f / Dc);
    const float var  = s2 * (1.0f / Dc) - mean * mean;
    const float rs   = rsqrtf(var + 1e-5f);
    union { uint4 u; bf16 h[8]; } st;
#pragma unroll
    for (int j = 0; j < 8; ++j) {
        const int col = t * 8 + j;
        st.h[j] = f2bf((f[j] - mean) * rs * w[col] + b[col]);
    }
    *(uint4*)&y[(size_t)row * Dc + t * 8] = st.u;
}

// ---- GEMM C[M,N] = epi(A[M,K] @ W[N,K]^T + bias), all-bf16, m97-style glds staging ----
// EPI: 0 plain, 1 *scale, 2 exact GELU, 3 +residual. RESF32: residual dtype. OUTF32: C dtype.
template<int EPI, int RESF32, int OUTF32>
__global__ __launch_bounds__(256)
void gemm_bt(const bf16* __restrict__ A, const bf16* __restrict__ W,
             const float* __restrict__ bias, const void* __restrict__ res,
             void* __restrict__ C, int M, int N, int K, float scale)
{
    __shared__ __align__(16) bf16 As[128 * 32];
    __shared__ __align__(16) bf16 Bs[128 * 32];
    const int tile_m = blockIdx.y * 128;
    const int tile_n = blockIdx.x * 128;
    const int t = threadIdx.x;
    const int wave = t >> 6, lane = t & 63, quad = lane >> 4, l16 = lane & 15;
    const int wm = (wave >> 1) * 64, wn = (wave & 1) * 64;

    floatx4 acc[4][4] = {};

    // staging: thread t covers row t>>2, 16B chunk t&3; LDS byte = t*16 (contiguous per wave)
    const bf16* Ag  = A + (size_t)(tile_m + (t >> 2)) * K + (t & 3) * 8;
    const bf16* Ag2 = Ag + (size_t)64 * K;
    const bf16* Wg  = W + (size_t)(tile_n + (t >> 2)) * K + (t & 3) * 8;
    const bf16* Wg2 = Wg + (size_t)64 * K;
    char* AsB = (char*)As;
    char* BsB = (char*)Bs;
    const int wbase = wave * 1024;

    for (int k0 = 0; k0 < K; k0 += 32) {
        __syncthreads();
        glds16(AsB + wbase,        Ag  + k0);
        glds16(AsB + 4096 + wbase, Ag2 + k0);
        glds16(BsB + wbase,        Wg  + k0);
        glds16(BsB + 4096 + wbase, Wg2 + k0);
        __syncthreads();
        short8 af[4], bfr[4];
#pragma unroll
        for (int mi = 0; mi < 4; ++mi)
            af[mi] = *(const short8*)&As[(wm + mi * 16 + l16) * 32 + quad * 8];
#pragma unroll
        for (int ni = 0; ni < 4; ++ni)
            bfr[ni] = *(const short8*)&Bs[(wn + ni * 16 + l16) * 32 + quad * 8];
#pragma unroll
        for (int mi = 0; mi < 4; ++mi)
#pragma unroll
            for (int ni = 0; ni < 4; ++ni)
                acc[mi][ni] = __builtin_amdgcn_mfma_f32_16x16x32_bf16(af[mi], bfr[ni], acc[mi][ni], 0, 0, 0);
    }

#pragma unroll
    for (int mi = 0; mi < 4; ++mi) {
        const int row0 = tile_m + wm + mi * 16 + quad * 4;
#pragma unroll
        for (int ni = 0; ni < 4; ++ni) {
            const int col = tile_n + wn + ni * 16 + l16;
            const float bv = bias[col];
#pragma unroll
            for (int r = 0; r < 4; ++r) {
                float v = acc[mi][ni][r] + bv;
                if (EPI == 1) v *= scale;
                if (EPI == 2) v = 0.5f * v * (1.0f + erff(v * 0.70710678118f));
                const size_t idx = (size_t)(row0 + r) * N + col;
                if (EPI == 3) v += RESF32 ? ((const float*)res)[idx] : bf2f(((const bf16*)res)[idx]);
                if (OUTF32) ((float*)C)[idx] = v;
                else        ((bf16*)C)[idx] = f2bf(v);
            }
        }
    }
}

// ---- Flash attention: one block per (64 q-rows, b*h); Q/K/V bf16 (ws), mask fp32 ------
__global__ __launch_bounds__(256)
void flash_attn(const bf16* __restrict__ Q, const bf16* __restrict__ K,
                const bf16* __restrict__ V, const float* __restrict__ mask,
                bf16* __restrict__ O)
{
    __shared__ __align__(16) bf16 Ks[32 * 128];
    __shared__ __align__(16) bf16 Vt[128 * 32];
    __shared__ __align__(16) bf16 Ps[4][16 * 32];
    const int bh = blockIdx.y, b = bh / Hc, h = bh % Hc;
    const int t = threadIdx.x, wave = t >> 6, lane = t & 63, quad = lane >> 4, l16 = lane & 15;
    const int qbase = blockIdx.x * 64 + wave * 16;
    const size_t base = (size_t)b * Sc * Dc + (size_t)h * HDc;

    short8 qf[4];
    {
        const bf16* qp = Q + base + (size_t)(qbase + l16) * Dc + quad * 8;
#pragma unroll
        for (int kc = 0; kc < 4; ++kc) qf[kc] = *(const short8*)(qp + kc * 32);
    }
    float m_i[4], l_i[4];
    floatx4 Oacc[8] = {};
#pragma unroll
    for (int r = 0; r < 4; ++r) { m_i[r] = -1e30f; l_i[r] = 0.f; }

    const int srow = t >> 4, scol = (t & 15) * 8;
    const int wbase = wave * 1024;

    for (int kt = 0; kt < Sc; kt += 32) {
        __syncthreads();
#pragma unroll
        for (int c = 0; c < 2; ++c) {
            const int row = c * 16 + srow;
            const size_t g = base + (size_t)(kt + row) * Dc + scol;
            glds16((char*)Ks + c * 4096 + wbase, &K[g]);   // LDS byte = c*4096 + t*16
            union { uint4 u; bf16 e[8]; } vv;
            vv.u = *(const uint4*)&V[g];
#pragma unroll
            for (int j = 0; j < 8; ++j) Vt[(scol + j) * 32 + row] = vv.e[j];
        }
        __syncthreads();

        floatx4 sacc[2] = {};
#pragma unroll
        for (int sub = 0; sub < 2; ++sub)
#pragma unroll
            for (int kc = 0; kc < 4; ++kc) {
                short8 kf = *(const short8*)&Ks[(sub * 16 + l16) * 128 + kc * 32 + quad * 8];
                sacc[sub] = __builtin_amdgcn_mfma_f32_16x16x32_bf16(qf[kc], kf, sacc[sub], 0, 0, 0);
            }
#pragma unroll
        for (int sub = 0; sub < 2; ++sub) {
            const float mv = mask[b * Sc + kt + sub * 16 + l16];
            const float madd = (mv < 0.5f) ? -1e30f : 0.f;
#pragma unroll
            for (int r = 0; r < 4; ++r) sacc[sub][r] += madd;
        }
        float p0[4], p1[4], alpha[4];
#pragma unroll
        for (int r = 0; r < 4; ++r) {
            float mx = fmaxf(sacc[0][r], sacc[1][r]);
#pragma unroll
            for (int off = 8; off; off >>= 1) mx = fmaxf(mx, __shfl_xor(mx, off));
            const float mnew = fmaxf(m_i[r], mx);
            alpha[r] = expf(m_i[r] - mnew);
            p0[r] = expf(sacc[0][r] - mnew);
            p1[r] = expf(sacc[1][r] - mnew);
            float ps = p0[r] + p1[r];
#pragma unroll
            for (int off = 8; off; off >>= 1) ps += __shfl_xor(ps, off);
            l_i[r] = l_i[r] * alpha[r] + ps;
            m_i[r] = mnew;
        }
#pragma unroll
        for (int nsub = 0; nsub < 8; ++nsub)
#pragma unroll
            for (int r = 0; r < 4; ++r) Oacc[nsub][r] *= alpha[r];

        bf16* Pw = Ps[wave];
#pragma unroll
        for (int r = 0; r < 4; ++r) {
            Pw[(quad * 4 + r) * 32 + l16]      = f2bf(p0[r]);
            Pw[(quad * 4 + r) * 32 + 16 + l16] = f2bf(p1[r]);
        }
        __syncthreads();
        const short8 pf = *(const short8*)&Pw[l16 * 32 + quad * 8];
#pragma unroll
        for (int nsub = 0; nsub < 8; ++nsub) {
            short8 vf = *(const short8*)&Vt[(nsub * 16 + l16) * 32 + quad * 8];
            Oacc[nsub] = __builtin_amdgcn_mfma_f32_16x16x32_bf16(pf, vf, Oacc[nsub], 0, 0, 0);
        }
    }

#pragma unroll
    for (int r = 0; r < 4; ++r) {
        const float inv = 1.f / l_i[r];
        const size_t rowbase = base + (size_t)(qbase + quad * 4 + r) * Dc;
#pragma unroll
        for (int nsub = 0; nsub < 8; ++nsub)
            O[rowbase + nsub * 16 + l16] = f2bf(Oacc[nsub][r] * inv);
    }
}

// ---------------------------------- launcher ------------------------------------------
extern "C" void kernel_launch(void* const* d_in, const int* in_sizes, int n_in,
                              void* d_out, int out_size, void* d_ws, size_t ws_size,
                              hipStream_t stream)
{
    const float* hidden = (const float*)d_in[1];
    const float* amask  = (const float*)d_in[2];
    const float* Wq = (const float*)d_in[4];  const float* bq = (const float*)d_in[5];
    const float* Wk = (const float*)d_in[6];  const float* bk = (const float*)d_in[7];
    const float* Wv = (const float*)d_in[8];  const float* bv = (const float*)d_in[9];
    const float* Wo = (const float*)d_in[10]; const float* bo = (const float*)d_in[11];
    const float* ln1w = (const float*)d_in[12]; const float* ln1b = (const float*)d_in[13];
    const float* ln2w = (const float*)d_in[14]; const float* ln2b = (const float*)d_in[15];
    const float* W1 = (const float*)d_in[16]; const float* b1 = (const float*)d_in[17];
    const float* W2 = (const float*)d_in[18]; const float* b2 = (const float*)d_in[19];

    const size_t UE = 8ull * 1024 * 1024;     // elements per 16 MB bf16 unit
    const size_t WE = 4ull * 1024 * 1024;     // elements per D*D weight
    bf16* U = (bf16*)d_ws;
    bf16* x_ln  = U;                 // U0   (later ffn1 overlays U0-U3)
    bf16* q     = U + UE;            // U1
    bf16* k     = U + 2 * UE;        // U2
    bf16* v     = U + 3 * UE;        // U3
    bf16* hid2  = U + 4 * UE;        // U4
    bf16* wbuf  = U + 5 * UE;        // U5-U6 (32 MB): Wq..Wo, then W1, then W2
    bf16* ffn1  = U;                 // U0-U3 (64 MB)
    bf16* attn  = (bf16*)d_out;      // d_out first 16 MB  (dead before FFN2)
    bf16* y_ln  = (bf16*)d_out + UE; // d_out second 16 MB (dead before FFN2)

    const float scale = 0.08838834764831845f; // 128^-0.5
    const dim3 gSq(Dc / 128, Bc * Sc / 128);  // (16,32)
    const dim3 gF1(Ic / 128, Bc * Sc / 128);  // (64,32)

    conv_w<<<2048, 256, 0, stream>>>(Wq, wbuf);
    conv_w<<<2048, 256, 0, stream>>>(Wk, wbuf + WE);
    conv_w<<<2048, 256, 0, stream>>>(Wv, wbuf + 2 * WE);
    conv_w<<<2048, 256, 0, stream>>>(Wo, wbuf + 3 * WE);
    ln_kernel<1><<<Bc * Sc, 256, 0, stream>>>(hidden, ln1w, ln1b, x_ln);
    gemm_bt<1,0,0><<<gSq, 256, 0, stream>>>(x_ln, wbuf,          bq, nullptr, q, Bc * Sc, Dc, Dc, scale);
    gemm_bt<0,0,0><<<gSq, 256, 0, stream>>>(x_ln, wbuf + WE,     bk, nullptr, k, Bc * Sc, Dc, Dc, 0.f);
    gemm_bt<0,0,0><<<gSq, 256, 0, stream>>>(x_ln, wbuf + 2 * WE, bv, nullptr, v, Bc * Sc, Dc, Dc, 0.f);
    flash_attn<<<dim3(Sc / 64, Bc * Hc), 256, 0, stream>>>(q, k, v, amask, attn);
    gemm_bt<3,1,0><<<gSq, 256, 0, stream>>>(attn, wbuf + 3 * WE, bo, hidden, hid2, Bc * Sc, Dc, Dc, 0.f);
    ln_kernel<0><<<Bc * Sc, 256, 0, stream>>>(hid2, ln2w, ln2b, y_ln);
    conv_w<<<8192, 256, 0, stream>>>(W1, wbuf);
    gemm_bt<2,0,0><<<gF1, 256, 0, stream>>>(y_ln, wbuf, b1, nullptr, ffn1, Bc * Sc, Ic, Dc, 0.f);
    conv_w<<<8192, 256, 0, stream>>>(W2, wbuf);
    gemm_bt<3,0,1><<<gSq, 256, 0, stream>>>(ffn1, wbuf, b2, hid2, d_out, Bc * Sc, Dc, Ic, 0.f);
}

// Round 4
// 994.418 us; speedup vs baseline: 1.6030x; 1.1567x over previous
//
#include <hip/hip_runtime.h>
#include <hip/hip_bf16.h>
#include <math.h>

typedef __hip_bfloat16 bf16;
typedef __attribute__((ext_vector_type(8))) short short8;
typedef __attribute__((ext_vector_type(4))) float floatx4;

constexpr int Bc = 4, Sc = 1024, Dc = 2048, Hc = 16, HDc = 128, Ic = 8192;
constexpr int QKVLD = 3 * Dc;  // 6144

__device__ __forceinline__ float bf2f(bf16 x){ return __bfloat162float(x); }
__device__ __forceinline__ bf16 f2bf(float x){ return __float2bfloat16(x); }

__device__ __forceinline__ uint4 pack8(float4 a, float4 b){
    union { uint4 u; bf16 h[8]; } r;
    r.h[0]=f2bf(a.x); r.h[1]=f2bf(a.y); r.h[2]=f2bf(a.z); r.h[3]=f2bf(a.w);
    r.h[4]=f2bf(b.x); r.h[5]=f2bf(b.y); r.h[6]=f2bf(b.z); r.h[7]=f2bf(b.w);
    return r.u;
}

// async global->LDS, 16B/lane; lds must be the WAVE-UNIFORM base (deposit = base + lane*16)
__device__ __forceinline__ void glds16(void* lds, const void* g){
    __builtin_amdgcn_global_load_lds(
        (__attribute__((address_space(1))) void*)(size_t)g,
        (__attribute__((address_space(3))) void*)lds,
        16, 0, 0);
}

// ---- weight convert fp32 -> bf16, 8 el/thread -----------------------------------------
__global__ __launch_bounds__(256)
void conv_w(const float* __restrict__ src, bf16* __restrict__ dst){
    const size_t i = ((size_t)blockIdx.x * 256 + threadIdx.x) * 8;
    float4 a = *(const float4*)(src + i);
    float4 b = *(const float4*)(src + i + 4);
    *(uint4*)(dst + i) = pack8(a, b);
}

// ---- LayerNorm: one block per row, D=2048, 256 thr x 8 el; INF32: input dtype ---------
template<int INF32>
__global__ __launch_bounds__(256)
void ln_kernel(const void* __restrict__ x, const float* __restrict__ w,
               const float* __restrict__ b, bf16* __restrict__ y)
{
    const int row = blockIdx.x;
    const int t = threadIdx.x;
    float f[8], s = 0.f, s2 = 0.f;
    if (INF32) {
        const float* xr = (const float*)x + (size_t)row * Dc + t * 8;
        float4 a = *(const float4*)xr, c = *(const float4*)(xr + 4);
        f[0]=a.x; f[1]=a.y; f[2]=a.z; f[3]=a.w; f[4]=c.x; f[5]=c.y; f[6]=c.z; f[7]=c.w;
    } else {
        union { uint4 u; bf16 h[8]; } ld;
        ld.u = *(const uint4*)((const bf16*)x + (size_t)row * Dc + t * 8);
#pragma unroll
        for (int j = 0; j < 8; ++j) f[j] = bf2f(ld.h[j]);
    }
#pragma unroll
    for (int j = 0; j < 8; ++j) { s += f[j]; s2 += f[j] * f[j]; }
#pragma unroll
    for (int off = 32; off; off >>= 1) { s += __shfl_xor(s, off); s2 += __shfl_xor(s2, off); }
    __shared__ float red[8];
    const int wave = t >> 6, lane = t & 63;
    if (lane == 0) { red[wave] = s; red[4 + wave] = s2; }
    __syncthreads();
    s  = red[0] + red[1] + red[2] + red[3];
    s2 = red[4] + red[5] + red[6] + red[7];
    const float mean = s * (1.0f / Dc);
    const float var  = s2 * (1.0f / Dc) - mean * mean;
    const float rs   = rsqrtf(var + 1e-5f);
    union { uint4 u; bf16 h[8]; } st;
#pragma unroll
    for (int j = 0; j < 8; ++j) {
        const int col = t * 8 + j;
        st.h[j] = f2bf((f[j] - mean) * rs * w[col] + b[col]);
    }
    *(uint4*)&y[(size_t)row * Dc + t * 8] = st.u;
}

// ---- GEMM C[M,N] = epi(A[M,K] @ W[N,K]^T + bias), all-bf16, m97-style glds staging ----
// EPI: 0 plain, 1 *scale, 2 exact GELU, 3 +residual, 4 fused-QKV (bias/scale by col)
template<int EPI, int RESF32, int OUTF32>
__global__ __launch_bounds__(256)
void gemm_bt(const bf16* __restrict__ A, const bf16* __restrict__ W,
             const float* __restrict__ bias, const float* __restrict__ bias2,
             const float* __restrict__ bias3, const void* __restrict__ res,
             void* __restrict__ C, int M, int N, int K, float scale)
{
    __shared__ __align__(16) bf16 As[128 * 32];
    __shared__ __align__(16) bf16 Bs[128 * 32];
    const int tile_m = blockIdx.y * 128;
    const int tile_n = blockIdx.x * 128;
    const int t = threadIdx.x;
    const int wave = t >> 6, lane = t & 63, quad = lane >> 4, l16 = lane & 15;
    const int wm = (wave >> 1) * 64, wn = (wave & 1) * 64;

    floatx4 acc[4][4] = {};

    const bf16* Ag  = A + (size_t)(tile_m + (t >> 2)) * K + (t & 3) * 8;
    const bf16* Ag2 = Ag + (size_t)64 * K;
    const bf16* Wg  = W + (size_t)(tile_n + (t >> 2)) * K + (t & 3) * 8;
    const bf16* Wg2 = Wg + (size_t)64 * K;
    char* AsB = (char*)As;
    char* BsB = (char*)Bs;
    const int wbase = wave * 1024;

    for (int k0 = 0; k0 < K; k0 += 32) {
        __syncthreads();
        glds16(AsB + wbase,        Ag  + k0);
        glds16(AsB + 4096 + wbase, Ag2 + k0);
        glds16(BsB + wbase,        Wg  + k0);
        glds16(BsB + 4096 + wbase, Wg2 + k0);
        __syncthreads();
        short8 af[4], bfr[4];
#pragma unroll
        for (int mi = 0; mi < 4; ++mi)
            af[mi] = *(const short8*)&As[(wm + mi * 16 + l16) * 32 + quad * 8];
#pragma unroll
        for (int ni = 0; ni < 4; ++ni)
            bfr[ni] = *(const short8*)&Bs[(wn + ni * 16 + l16) * 32 + quad * 8];
#pragma unroll
        for (int mi = 0; mi < 4; ++mi)
#pragma unroll
            for (int ni = 0; ni < 4; ++ni)
                acc[mi][ni] = __builtin_amdgcn_mfma_f32_16x16x32_bf16(af[mi], bfr[ni], acc[mi][ni], 0, 0, 0);
    }

#pragma unroll
    for (int mi = 0; mi < 4; ++mi) {
        const int row0 = tile_m + wm + mi * 16 + quad * 4;
#pragma unroll
        for (int ni = 0; ni < 4; ++ni) {
            const int col = tile_n + wn + ni * 16 + l16;
            float bv, sc = 1.f;
            if (EPI == 4) {
                if (col < 2048)      { bv = bias[col];         sc = scale; }
                else if (col < 4096) { bv = bias2[col - 2048]; }
                else                 { bv = bias3[col - 4096]; }
            } else {
                bv = bias[col];
            }
#pragma unroll
            for (int r = 0; r < 4; ++r) {
                float v = acc[mi][ni][r] + bv;
                if (EPI == 1) v *= scale;
                if (EPI == 4) v *= sc;
                if (EPI == 2) v = 0.5f * v * (1.0f + erff(v * 0.70710678118f));
                const size_t idx = (size_t)(row0 + r) * N + col;
                if (EPI == 3) v += RESF32 ? ((const float*)res)[idx] : bf2f(((const bf16*)res)[idx]);
                if (OUTF32) ((float*)C)[idx] = v;
                else        ((bf16*)C)[idx] = f2bf(v);
            }
        }
    }
}

// ---- Flash attention v2: block = 64 q-rows x (b,h); 4 waves x 16 q-rows; K-tile 64 ----
// QKV fused input [B*S][6144] bf16 (q scaled by HD^-0.5 * log2e already).
// LDS: Ks[kc4][key64][32] (glds16), Vt[d128][key64 pad72] (b32-pair transpose), Ps pad72.
__global__ __launch_bounds__(256)
void flash_attn(const bf16* __restrict__ QKV, const float* __restrict__ mask,
                bf16* __restrict__ O)
{
    __shared__ __align__(16) bf16 Ks[4 * 64 * 32];   // 16 KB
    __shared__ __align__(16) bf16 Vt[128 * 72];      // 18 KB
    __shared__ __align__(16) bf16 Ps[4][16 * 72];    // 9 KB
    const int bh = blockIdx.y, b = bh >> 4, h = bh & 15;
    const int t = threadIdx.x, w = t >> 6, lane = t & 63, quad = lane >> 4, l16 = lane & 15;
    const int qbase = blockIdx.x * 64 + w * 16;
    const size_t rowb = (size_t)b * Sc;
    const bf16* Kp = QKV + 2048 + (size_t)h * HDc;
    const bf16* Vp = QKV + 4096 + (size_t)h * HDc;

    // Q fragments: A[m=l16][k=quad*8+j], 4 chunks of 32 cover HD=128
    short8 qf[4];
    {
        const bf16* qp = QKV + (rowb + qbase + l16) * QKVLD + (size_t)h * HDc + quad * 8;
#pragma unroll
        for (int kc = 0; kc < 4; ++kc) qf[kc] = *(const short8*)(qp + kc * 32);
    }
    float m_i[4], l_i[4];
    floatx4 Oacc[8] = {};
#pragma unroll
    for (int r = 0; r < 4; ++r) { m_i[r] = -1e30f; l_i[r] = 0.f; }

    const int p2 = t & 31, dg = t >> 5;   // Vt staging: key-pair, d-group

    for (int kt = 0; kt < Sc; kt += 64) {
        __syncthreads();
        // Ks: wave w stages kc=w (4 units of 16 keys); deposit = base + lane*16
#pragma unroll
        for (int u = 0; u < 4; ++u) {
            const int row = u * 16 + (lane >> 2);
            glds16((char*)Ks + w * 4096 + u * 1024,
                   Kp + (rowb + kt + row) * QKVLD + w * 32 + (lane & 3) * 8);
        }
        // Vt: thread loads keys (2p2, 2p2+1) x 16 d, writes key-pair-packed b32
        {
            union { uint4 u4; unsigned short s[8]; } va[2][2];
#pragma unroll
            for (int kk = 0; kk < 2; ++kk) {
                const bf16* vp = Vp + (rowb + kt + 2 * p2 + kk) * QKVLD + dg * 16;
                va[kk][0].u4 = *(const uint4*)vp;
                va[kk][1].u4 = *(const uint4*)(vp + 8);
            }
            unsigned* VtW = (unsigned*)Vt;
#pragma unroll
            for (int j = 0; j < 16; ++j) {
                const unsigned word = (unsigned)va[0][j >> 3].s[j & 7]
                                    | ((unsigned)va[1][j >> 3].s[j & 7] << 16);
                VtW[(dg * 16 + j) * 36 + p2] = word;   // Vt[d][2*p2..2*p2+1]
            }
        }
        __syncthreads();

        // S = Q @ K^T : 4 key-subtiles of 16
        floatx4 sacc[4] = {};
#pragma unroll
        for (int kc = 0; kc < 4; ++kc)
#pragma unroll
            for (int sub = 0; sub < 4; ++sub) {
                short8 kf = *(const short8*)&Ks[kc * 2048 + (sub * 16 + l16) * 32 + quad * 8];
                sacc[sub] = __builtin_amdgcn_mfma_f32_16x16x32_bf16(qf[kc], kf, sacc[sub], 0, 0, 0);
            }
        // additive key mask (log2 domain)
#pragma unroll
        for (int sub = 0; sub < 4; ++sub) {
            const float mv = mask[b * Sc + kt + sub * 16 + l16];
            const float madd = (mv < 0.5f) ? -3.0e38f : 0.f;
#pragma unroll
            for (int r = 0; r < 4; ++r) sacc[sub][r] += madd;
        }
        // online softmax (base-2)
        float p[4][4], alpha[4];
#pragma unroll
        for (int r = 0; r < 4; ++r) {
            float mx = fmaxf(fmaxf(sacc[0][r], sacc[1][r]), fmaxf(sacc[2][r], sacc[3][r]));
#pragma unroll
            for (int off = 8; off; off >>= 1) mx = fmaxf(mx, __shfl_xor(mx, off));
            const float mnew = fmaxf(m_i[r], mx);
            alpha[r] = exp2f(m_i[r] - mnew);
            float ps = 0.f;
#pragma unroll
            for (int sub = 0; sub < 4; ++sub) { p[sub][r] = exp2f(sacc[sub][r] - mnew); ps += p[sub][r]; }
#pragma unroll
            for (int off = 8; off; off >>= 1) ps += __shfl_xor(ps, off);
            l_i[r] = l_i[r] * alpha[r] + ps;
            m_i[r] = mnew;
        }
#pragma unroll
        for (int nsub = 0; nsub < 8; ++nsub)
#pragma unroll
            for (int r = 0; r < 4; ++r) Oacc[nsub][r] *= alpha[r];

        // P: C-layout -> A-layout via per-wave LDS (NO barrier: wave-private, DS in-order)
        bf16* Pw = Ps[w];
#pragma unroll
        for (int sub = 0; sub < 4; ++sub)
#pragma unroll
            for (int r = 0; r < 4; ++r)
                Pw[(quad * 4 + r) * 72 + sub * 16 + l16] = f2bf(p[sub][r]);
        const short8 pf0 = *(const short8*)&Pw[l16 * 72 + quad * 8];
        const short8 pf1 = *(const short8*)&Pw[l16 * 72 + 32 + quad * 8];
        // O += P @ V (8 d-subtiles, 2 key-chunks)
#pragma unroll
        for (int nsub = 0; nsub < 8; ++nsub) {
            const short8 vf0 = *(const short8*)&Vt[(nsub * 16 + l16) * 72 + quad * 8];
            const short8 vf1 = *(const short8*)&Vt[(nsub * 16 + l16) * 72 + 32 + quad * 8];
            Oacc[nsub] = __builtin_amdgcn_mfma_f32_16x16x32_bf16(pf0, vf0, Oacc[nsub], 0, 0, 0);
            Oacc[nsub] = __builtin_amdgcn_mfma_f32_16x16x32_bf16(pf1, vf1, Oacc[nsub], 0, 0, 0);
        }
    }

#pragma unroll
    for (int r = 0; r < 4; ++r) {
        const float inv = 1.f / l_i[r];
        bf16* orow = O + (rowb + qbase + quad * 4 + r) * Dc + (size_t)h * HDc;
#pragma unroll
        for (int nsub = 0; nsub < 8; ++nsub)
            orow[nsub * 16 + l16] = f2bf(Oacc[nsub][r] * inv);
    }
}

// ---------------------------------- launcher ------------------------------------------
extern "C" void kernel_launch(void* const* d_in, const int* in_sizes, int n_in,
                              void* d_out, int out_size, void* d_ws, size_t ws_size,
                              hipStream_t stream)
{
    const float* hidden = (const float*)d_in[1];
    const float* amask  = (const float*)d_in[2];
    const float* Wq = (const float*)d_in[4];  const float* bq = (const float*)d_in[5];
    const float* Wk = (const float*)d_in[6];  const float* bk = (const float*)d_in[7];
    const float* Wv = (const float*)d_in[8];  const float* bv = (const float*)d_in[9];
    const float* Wo = (const float*)d_in[10]; const float* bo = (const float*)d_in[11];
    const float* ln1w = (const float*)d_in[12]; const float* ln1b = (const float*)d_in[13];
    const float* ln2w = (const float*)d_in[14]; const float* ln2b = (const float*)d_in[15];
    const float* W1 = (const float*)d_in[16]; const float* b1 = (const float*)d_in[17];
    const float* W2 = (const float*)d_in[18]; const float* b2 = (const float*)d_in[19];

    const size_t UE = 8ull * 1024 * 1024;     // elements per 16 MB bf16 unit
    const size_t WE = 4ull * 1024 * 1024;     // elements per D*D weight
    bf16* U = (bf16*)d_ws;
    bf16* qkv   = U;                 // U0-U2 (48 MB) [4096][6144]
    bf16* wbuf  = U + 4 * UE;        // U4-U5 (32 MB): Wq|Wk|Wv|Wo, then W1, then W2
    bf16* x_ln  = U + 6 * UE;        // U6
    bf16* hid2  = U + 6 * UE;        // U6 (overwrites x_ln after last use)
    bf16* ffn1  = U;                 // U0-U3 (64 MB; qkv dead)
    bf16* attn  = (bf16*)d_out;      // d_out[0:16MB)  (dead before final write)
    bf16* y_ln  = (bf16*)d_out + UE; // d_out[16:32MB) (dead before final write)

    // q scale folded with log2(e) for base-2 online softmax
    const float qscale = 0.08838834764831845f * 1.4426950408889634f;
    const dim3 gQKV(QKVLD / 128, Bc * Sc / 128);  // (48,32)
    const dim3 gSq (Dc / 128,    Bc * Sc / 128);  // (16,32)
    const dim3 gF1 (Ic / 128,    Bc * Sc / 128);  // (64,32)

    conv_w<<<2048, 256, 0, stream>>>(Wq, wbuf);
    conv_w<<<2048, 256, 0, stream>>>(Wk, wbuf + WE);
    conv_w<<<2048, 256, 0, stream>>>(Wv, wbuf + 2 * WE);
    conv_w<<<2048, 256, 0, stream>>>(Wo, wbuf + 3 * WE);
    ln_kernel<1><<<Bc * Sc, 256, 0, stream>>>(hidden, ln1w, ln1b, x_ln);
    gemm_bt<4,0,0><<<gQKV, 256, 0, stream>>>(x_ln, wbuf, bq, bk, bv, nullptr, qkv,
                                             Bc * Sc, QKVLD, Dc, qscale);
    flash_attn<<<dim3(Sc / 64, Bc * Hc), 256, 0, stream>>>(qkv, amask, attn);
    gemm_bt<3,1,0><<<gSq, 256, 0, stream>>>(attn, wbuf + 3 * WE, bo, nullptr, nullptr, hidden, hid2,
                                            Bc * Sc, Dc, Dc, 0.f);
    ln_kernel<0><<<Bc * Sc, 256, 0, stream>>>(hid2, ln2w, ln2b, y_ln);
    conv_w<<<8192, 256, 0, stream>>>(W1, wbuf);
    gemm_bt<2,0,0><<<gF1, 256, 0, stream>>>(y_ln, wbuf, b1, nullptr, nullptr, nullptr, ffn1,
                                            Bc * Sc, Ic, Dc, 0.f);
    conv_w<<<8192, 256, 0, stream>>>(W2, wbuf);
    gemm_bt<3,0,1><<<gSq, 256, 0, stream>>>(ffn1, wbuf, b2, nullptr, nullptr, hid2, d_out,
                                            Bc * Sc, Dc, Ic, 0.f);
}

// Round 5
// 990.790 us; speedup vs baseline: 1.6089x; 1.0037x over previous
//
#include <hip/hip_runtime.h>
#include <hip/hip_bf16.h>
#include <math.h>

typedef __hip_bfloat16 bf16;
typedef __attribute__((ext_vector_type(8))) short short8;
typedef __attribute__((ext_vector_type(4))) float floatx4;

constexpr int Bc = 4, Sc = 1024, Dc = 2048, Hc = 16, HDc = 128, Ic = 8192;
constexpr int QKVLD = 3 * Dc;  // 6144

__device__ __forceinline__ float bf2f(bf16 x){ return __bfloat162float(x); }
__device__ __forceinline__ bf16 f2bf(float x){ return __float2bfloat16(x); }

__device__ __forceinline__ uint4 pack8(float4 a, float4 b){
    union { uint4 u; bf16 h[8]; } r;
    r.h[0]=f2bf(a.x); r.h[1]=f2bf(a.y); r.h[2]=f2bf(a.z); r.h[3]=f2bf(a.w);
    r.h[4]=f2bf(b.x); r.h[5]=f2bf(b.y); r.h[6]=f2bf(b.z); r.h[7]=f2bf(b.w);
    return r.u;
}

// async global->LDS, 16B/lane; lds must be the WAVE-UNIFORM base (deposit = base + lane*16)
__device__ __forceinline__ void glds16(void* lds, const void* g){
    __builtin_amdgcn_global_load_lds(
        (__attribute__((address_space(1))) void*)(size_t)g,
        (__attribute__((address_space(3))) void*)lds,
        16, 0, 0);
}

// ---- weight convert fp32 -> bf16, 8 el/thread -----------------------------------------
__global__ __launch_bounds__(256)
void conv_w(const float* __restrict__ src, bf16* __restrict__ dst){
    const size_t i = ((size_t)blockIdx.x * 256 + threadIdx.x) * 8;
    float4 a = *(const float4*)(src + i);
    float4 b = *(const float4*)(src + i + 4);
    *(uint4*)(dst + i) = pack8(a, b);
}

// ---- 4 D*D weights in one launch (2048 blocks each) -----------------------------------
__global__ __launch_bounds__(256)
void conv_w4(const float* __restrict__ s0, const float* __restrict__ s1,
             const float* __restrict__ s2, const float* __restrict__ s3,
             bf16* __restrict__ dst){
    const int id = blockIdx.x >> 11;
    const float* src = (id == 0) ? s0 : (id == 1) ? s1 : (id == 2) ? s2 : s3;
    const size_t i = ((size_t)(blockIdx.x & 2047) * 256 + threadIdx.x) * 8;
    float4 a = *(const float4*)(src + i);
    float4 b = *(const float4*)(src + i + 4);
    *(uint4*)(dst + (size_t)id * Dc * Dc + i) = pack8(a, b);
}

// ---- dst[i] = bias[i % D] + src[i]  (fp32, 8 el/thread) -------------------------------
__global__ __launch_bounds__(256)
void init_add(float* __restrict__ dst, const float* __restrict__ bias,
              const float* __restrict__ src){
    const size_t i = ((size_t)blockIdx.x * 256 + threadIdx.x) * 8;
    const int col = (int)(i & (Dc - 1));
    float4 a = *(const float4*)(src + i);
    float4 b = *(const float4*)(src + i + 4);
    float4 ba = *(const float4*)(bias + col);
    float4 bb = *(const float4*)(bias + col + 4);
    a.x += ba.x; a.y += ba.y; a.z += ba.z; a.w += ba.w;
    b.x += bb.x; b.y += bb.y; b.z += bb.z; b.w += bb.w;
    *(float4*)(dst + i) = a;
    *(float4*)(dst + i + 4) = b;
}

// ---- LayerNorm: one block per row, D=2048, 256 thr x 8 el; INF32: input dtype ---------
template<int INF32>
__global__ __launch_bounds__(256)
void ln_kernel(const void* __restrict__ x, const float* __restrict__ w,
               const float* __restrict__ b, bf16* __restrict__ y)
{
    const int row = blockIdx.x;
    const int t = threadIdx.x;
    float f[8], s = 0.f, s2 = 0.f;
    if (INF32) {
        const float* xr = (const float*)x + (size_t)row * Dc + t * 8;
        float4 a = *(const float4*)xr, c = *(const float4*)(xr + 4);
        f[0]=a.x; f[1]=a.y; f[2]=a.z; f[3]=a.w; f[4]=c.x; f[5]=c.y; f[6]=c.z; f[7]=c.w;
    } else {
        union { uint4 u; bf16 h[8]; } ld;
        ld.u = *(const uint4*)((const bf16*)x + (size_t)row * Dc + t * 8);
#pragma unroll
        for (int j = 0; j < 8; ++j) f[j] = bf2f(ld.h[j]);
    }
#pragma unroll
    for (int j = 0; j < 8; ++j) { s += f[j]; s2 += f[j] * f[j]; }
#pragma unroll
    for (int off = 32; off; off >>= 1) { s += __shfl_xor(s, off); s2 += __shfl_xor(s2, off); }
    __shared__ float red[8];
    const int wave = t >> 6, lane = t & 63;
    if (lane == 0) { red[wave] = s; red[4 + wave] = s2; }
    __syncthreads();
    s  = red[0] + red[1] + red[2] + red[3];
    s2 = red[4] + red[5] + red[6] + red[7];
    const float mean = s * (1.0f / Dc);
    const float var  = s2 * (1.0f / Dc) - mean * mean;
    const float rs   = rsqrtf(var + 1e-5f);
    union { uint4 u; bf16 h[8]; } st;
#pragma unroll
    for (int j = 0; j < 8; ++j) {
        const int col = t * 8 + j;
        st.h[j] = f2bf((f[j] - mean) * rs * w[col] + b[col]);
    }
    *(uint4*)&y[(size_t)row * Dc + t * 8] = st.u;
}

// ---- GEMM C[M,N] = epi(A[M,K] @ W[N,K]^T + bias), BK=64, swizzled LDS, glds16 ---------
// EPI: 0 plain, 1 *scale, 2 exact GELU, 3 +residual, 4 fused-QKV, 5 atomic fp32 (no bias)
// split-K via blockIdx.z (gridDim.z splits; EPI=5 accumulates atomically).
template<int EPI, int RESF32, int OUTF32>
__global__ __launch_bounds__(256)
void gemm_bt(const bf16* __restrict__ A, const bf16* __restrict__ W,
             const float* __restrict__ bias, const float* __restrict__ bias2,
             const float* __restrict__ bias3, const void* __restrict__ res,
             void* __restrict__ C, int M, int N, int K, float scale)
{
    __shared__ __align__(16) bf16 As[128 * 64];   // 16 KB
    __shared__ __align__(16) bf16 Bs[128 * 64];   // 16 KB
    const int tile_m = blockIdx.y * 128;
    const int tile_n = blockIdx.x * 128;
    const int t = threadIdx.x;
    const int wave = t >> 6, lane = t & 63, quad = lane >> 4, l16 = lane & 15;
    const int wm = (wave >> 1) * 64, wn = (wave & 1) * 64;
    const int Klen = K / gridDim.z, kbeg = blockIdx.z * Klen;

    floatx4 acc[4][4] = {};

    // staging: call u (0..3): row = u*32 + (t>>3); stored chunk = t&7; global chunk = (c-row)&7
    const int r8 = t >> 3, c8 = t & 7;
    const int cg = (c8 - r8) & 7;
    const bf16* Ab = A + (size_t)(tile_m + r8) * K + kbeg + cg * 8;
    const bf16* Wb = W + (size_t)(tile_n + r8) * K + kbeg + cg * 8;
    char* AsB = (char*)As;
    char* BsB = (char*)Bs;
    const int wb = wave * 1024;

    for (int k0 = 0; k0 < Klen; k0 += 64) {
        __syncthreads();
#pragma unroll
        for (int u = 0; u < 4; ++u) {
            glds16(AsB + u * 4096 + wb, Ab + (size_t)(u * 32) * K + k0);
            glds16(BsB + u * 4096 + wb, Wb + (size_t)(u * 32) * K + k0);
        }
        __syncthreads();
#pragma unroll
        for (int ks = 0; ks < 2; ++ks) {
            short8 af[4], bfr[4];
#pragma unroll
            for (int mi = 0; mi < 4; ++mi)
                af[mi] = *(const short8*)&As[(wm + mi * 16 + l16) * 64 + ((ks * 4 + quad + l16) & 7) * 8];
#pragma unroll
            for (int ni = 0; ni < 4; ++ni)
                bfr[ni] = *(const short8*)&Bs[(wn + ni * 16 + l16) * 64 + ((ks * 4 + quad + l16) & 7) * 8];
#pragma unroll
            for (int mi = 0; mi < 4; ++mi)
#pragma unroll
                for (int ni = 0; ni < 4; ++ni)
                    acc[mi][ni] = __builtin_amdgcn_mfma_f32_16x16x32_bf16(af[mi], bfr[ni], acc[mi][ni], 0, 0, 0);
        }
    }

#pragma unroll
    for (int mi = 0; mi < 4; ++mi) {
        const int row0 = tile_m + wm + mi * 16 + quad * 4;
#pragma unroll
        for (int ni = 0; ni < 4; ++ni) {
            const int col = tile_n + wn + ni * 16 + l16;
            float bv = 0.f, sc = 1.f;
            if (EPI == 4) {
                if (col < 2048)      { bv = bias[col];         sc = scale; }
                else if (col < 4096) { bv = bias2[col - 2048]; }
                else                 { bv = bias3[col - 4096]; }
            } else if (EPI != 5) {
                bv = bias[col];
            }
#pragma unroll
            for (int r = 0; r < 4; ++r) {
                const size_t idx = (size_t)(row0 + r) * N + col;
                float v = acc[mi][ni][r];
                if (EPI == 5) { atomicAdd(&((float*)C)[idx], v); continue; }
                v += bv;
                if (EPI == 1) v *= scale;
                if (EPI == 4) v *= sc;
                if (EPI == 2) v = 0.5f * v * (1.0f + erff(v * 0.70710678118f));
                if (EPI == 3) v += RESF32 ? ((const float*)res)[idx] : bf2f(((const bf16*)res)[idx]);
                if (OUTF32) ((float*)C)[idx] = v;
                else        ((bf16*)C)[idx] = f2bf(v);
            }
        }
    }
}

// ---- Flash attention v2 (unchanged from round 4) --------------------------------------
__global__ __launch_bounds__(256)
void flash_attn(const bf16* __restrict__ QKV, const float* __restrict__ mask,
                bf16* __restrict__ O)
{
    __shared__ __align__(16) bf16 Ks[4 * 64 * 32];
    __shared__ __align__(16) bf16 Vt[128 * 72];
    __shared__ __align__(16) bf16 Ps[4][16 * 72];
    const int bh = blockIdx.y, b = bh >> 4, h = bh & 15;
    const int t = threadIdx.x, w = t >> 6, lane = t & 63, quad = lane >> 4, l16 = lane & 15;
    const int qbase = blockIdx.x * 64 + w * 16;
    const size_t rowb = (size_t)b * Sc;
    const bf16* Kp = QKV + 2048 + (size_t)h * HDc;
    const bf16* Vp = QKV + 4096 + (size_t)h * HDc;

    short8 qf[4];
    {
        const bf16* qp = QKV + (rowb + qbase + l16) * QKVLD + (size_t)h * HDc + quad * 8;
#pragma unroll
        for (int kc = 0; kc < 4; ++kc) qf[kc] = *(const short8*)(qp + kc * 32);
    }
    float m_i[4], l_i[4];
    floatx4 Oacc[8] = {};
#pragma unroll
    for (int r = 0; r < 4; ++r) { m_i[r] = -1e30f; l_i[r] = 0.f; }

    const int p2 = t & 31, dg = t >> 5;

    for (int kt = 0; kt < Sc; kt += 64) {
        __syncthreads();
#pragma unroll
        for (int u = 0; u < 4; ++u) {
            const int row = u * 16 + (lane >> 2);
            glds16((char*)Ks + w * 4096 + u * 1024,
                   Kp + (rowb + kt + row) * QKVLD + w * 32 + (lane & 3) * 8);
        }
        {
            union { uint4 u4; unsigned short s[8]; } va[2][2];
#pragma unroll
            for (int kk = 0; kk < 2; ++kk) {
                const bf16* vp = Vp + (rowb + kt + 2 * p2 + kk) * QKVLD + dg * 16;
                va[kk][0].u4 = *(const uint4*)vp;
                va[kk][1].u4 = *(const uint4*)(vp + 8);
            }
            unsigned* VtW = (unsigned*)Vt;
#pragma unroll
            for (int j = 0; j < 16; ++j) {
                const unsigned word = (unsigned)va[0][j >> 3].s[j & 7]
                                    | ((unsigned)va[1][j >> 3].s[j & 7] << 16);
                VtW[(dg * 16 + j) * 36 + p2] = word;
            }
        }
        __syncthreads();

        floatx4 sacc[4] = {};
#pragma unroll
        for (int kc = 0; kc < 4; ++kc)
#pragma unroll
            for (int sub = 0; sub < 4; ++sub) {
                short8 kf = *(const short8*)&Ks[kc * 2048 + (sub * 16 + l16) * 32 + quad * 8];
                sacc[sub] = __builtin_amdgcn_mfma_f32_16x16x32_bf16(qf[kc], kf, sacc[sub], 0, 0, 0);
            }
#pragma unroll
        for (int sub = 0; sub < 4; ++sub) {
            const float mv = mask[b * Sc + kt + sub * 16 + l16];
            const float madd = (mv < 0.5f) ? -3.0e38f : 0.f;
#pragma unroll
            for (int r = 0; r < 4; ++r) sacc[sub][r] += madd;
        }
        float p[4][4], alpha[4];
#pragma unroll
        for (int r = 0; r < 4; ++r) {
            float mx = fmaxf(fmaxf(sacc[0][r], sacc[1][r]), fmaxf(sacc[2][r], sacc[3][r]));
#pragma unroll
            for (int off = 8; off; off >>= 1) mx = fmaxf(mx, __shfl_xor(mx, off));
            const float mnew = fmaxf(m_i[r], mx);
            alpha[r] = exp2f(m_i[r] - mnew);
            float ps = 0.f;
#pragma unroll
            for (int sub = 0; sub < 4; ++sub) { p[sub][r] = exp2f(sacc[sub][r] - mnew); ps += p[sub][r]; }
#pragma unroll
            for (int off = 8; off; off >>= 1) ps += __shfl_xor(ps, off);
            l_i[r] = l_i[r] * alpha[r] + ps;
            m_i[r] = mnew;
        }
#pragma unroll
        for (int nsub = 0; nsub < 8; ++nsub)
#pragma unroll
            for (int r = 0; r < 4; ++r) Oacc[nsub][r] *= alpha[r];

        bf16* Pw = Ps[w];
#pragma unroll
        for (int sub = 0; sub < 4; ++sub)
#pragma unroll
            for (int r = 0; r < 4; ++r)
                Pw[(quad * 4 + r) * 72 + sub * 16 + l16] = f2bf(p[sub][r]);
        const short8 pf0 = *(const short8*)&Pw[l16 * 72 + quad * 8];
        const short8 pf1 = *(const short8*)&Pw[l16 * 72 + 32 + quad * 8];
#pragma unroll
        for (int nsub = 0; nsub < 8; ++nsub) {
            const short8 vf0 = *(const short8*)&Vt[(nsub * 16 + l16) * 72 + quad * 8];
            const short8 vf1 = *(const short8*)&Vt[(nsub * 16 + l16) * 72 + 32 + quad * 8];
            Oacc[nsub] = __builtin_amdgcn_mfma_f32_16x16x32_bf16(pf0, vf0, Oacc[nsub], 0, 0, 0);
            Oacc[nsub] = __builtin_amdgcn_mfma_f32_16x16x32_bf16(pf1, vf1, Oacc[nsub], 0, 0, 0);
        }
    }

#pragma unroll
    for (int r = 0; r < 4; ++r) {
        const float inv = 1.f / l_i[r];
        bf16* orow = O + (rowb + qbase + quad * 4 + r) * Dc + (size_t)h * HDc;
#pragma unroll
        for (int nsub = 0; nsub < 8; ++nsub)
            orow[nsub * 16 + l16] = f2bf(Oacc[nsub][r] * inv);
    }
}

// ---------------------------------- launcher ------------------------------------------
extern "C" void kernel_launch(void* const* d_in, const int* in_sizes, int n_in,
                              void* d_out, int out_size, void* d_ws, size_t ws_size,
                              hipStream_t stream)
{
    const float* hidden = (const float*)d_in[1];
    const float* amask  = (const float*)d_in[2];
    const float* Wq = (const float*)d_in[4];  const float* bq = (const float*)d_in[5];
    const float* Wk = (const float*)d_in[6];  const float* bk = (const float*)d_in[7];
    const float* Wv = (const float*)d_in[8];  const float* bv = (const float*)d_in[9];
    const float* Wo = (const float*)d_in[10]; const float* bo = (const float*)d_in[11];
    const float* ln1w = (const float*)d_in[12]; const float* ln1b = (const float*)d_in[13];
    const float* ln2w = (const float*)d_in[14]; const float* ln2b = (const float*)d_in[15];
    const float* W1 = (const float*)d_in[16]; const float* b1 = (const float*)d_in[17];
    const float* W2 = (const float*)d_in[18]; const float* b2 = (const float*)d_in[19];

    const size_t UE = 8ull * 1024 * 1024;     // elements per 16 MB bf16 unit
    const size_t WE = 4ull * 1024 * 1024;     // elements per D*D weight
    bf16*  U = (bf16*)d_ws;
    bf16*  qkv   = U;                         // U0-U2 (48 MB) [4096][6144]
    bf16*  wbuf  = U + 4 * UE;                // U4-U5 (32 MB): Wq|Wk|Wv|Wo, then W1, then W2
    bf16*  x_ln  = U + 6 * UE;                // U6 (dead after QKV gemm)
    float* hid2f = (float*)(U + 6 * UE);      // U6-U7 fp32 32 MB (overlays x_ln)
    bf16*  ffn1  = U;                         // U0-U3 (64 MB; qkv dead)
    bf16*  attn  = (bf16*)d_out;              // d_out[0:16MB)
    bf16*  y_ln  = (bf16*)d_out + UE;         // d_out[16:32MB)
    float* outf  = (float*)d_out;

    const float qscale = 0.08838834764831845f * 1.4426950408889634f; // HD^-0.5 * log2e
    const dim3 gQKV(QKVLD / 128, Bc * Sc / 128, 1);  // (48,32)
    const dim3 gSK (Dc / 128,    Bc * Sc / 128, 2);  // (16,32,2) split-K
    const dim3 gF1 (Ic / 128,    Bc * Sc / 128, 1);  // (64,32)

    conv_w4<<<8192, 256, 0, stream>>>(Wq, Wk, Wv, Wo, wbuf);
    ln_kernel<1><<<Bc * Sc, 256, 0, stream>>>(hidden, ln1w, ln1b, x_ln);
    gemm_bt<4,0,0><<<gQKV, 256, 0, stream>>>(x_ln, wbuf, bq, bk, bv, nullptr, qkv,
                                             Bc * Sc, QKVLD, Dc, qscale);
    flash_attn<<<dim3(Sc / 64, Bc * Hc), 256, 0, stream>>>(qkv, amask, attn);
    init_add<<<4096, 256, 0, stream>>>(hid2f, bo, hidden);              // hid2f = bo + hidden
    gemm_bt<5,0,1><<<gSK, 256, 0, stream>>>(attn, wbuf + 3 * WE, nullptr, nullptr, nullptr,
                                            nullptr, hid2f, Bc * Sc, Dc, Dc, 0.f);
    ln_kernel<1><<<Bc * Sc, 256, 0, stream>>>(hid2f, ln2w, ln2b, y_ln);
    conv_w<<<8192, 256, 0, stream>>>(W1, wbuf);
    gemm_bt<2,0,0><<<gF1, 256, 0, stream>>>(y_ln, wbuf, b1, nullptr, nullptr, nullptr, ffn1,
                                            Bc * Sc, Ic, Dc, 0.f);
    init_add<<<4096, 256, 0, stream>>>(outf, b2, hid2f);                // d_out = b2 + hid2f
    conv_w<<<8192, 256, 0, stream>>>(W2, wbuf);
    gemm_bt<5,0,1><<<gSK, 256, 0, stream>>>(ffn1, wbuf, nullptr, nullptr, nullptr,
                                            nullptr, outf, Bc * Sc, Dc, Ic, 0.f);
}